// Round 5
// baseline (137.594 us; speedup 1.0000x reference)
//
#include <hip/hip_runtime.h>

#define Nn 768
#define Dd 128
#define LDP 136   // fallback-path padded bf16 row stride

typedef __attribute__((ext_vector_type(8))) short bf16x8;
typedef __attribute__((ext_vector_type(4))) float f32x4;
typedef __attribute__((ext_vector_type(4))) int   i32x4;

static __device__ __forceinline__ unsigned short f2bf(float f) {
  unsigned int u = __builtin_bit_cast(unsigned int, f);
  u += 0x7fffu + ((u >> 16) & 1u);   // RNE
  return (unsigned short)(u >> 16);
}
static __device__ __forceinline__ float bf2f(unsigned short h) {
  unsigned int u = ((unsigned int)h) << 16;
  return __builtin_bit_cast(float, u);
}

// ======================= fast path =======================
// k_prep: one block per i. Computes l_i = x_i*W_in^T + b_in, writes:
//   left_sw[i]  : bf16 row, 16B-chunks XOR-swizzled by ((i&7)<<4)
//   B_sw[i][e][d] = bf16(W_out[e][d] * l_i[d]), rows XOR-swizzled by ((e&7)<<4)
__global__ __launch_bounds__(256)
void k_prep(const float* __restrict__ x, const float* __restrict__ Win,
            const float* __restrict__ bin, const float* __restrict__ Wout,
            unsigned short* __restrict__ left_sw, unsigned short* __restrict__ B_sw) {
  __shared__ float sx[Dd];
  __shared__ float sLi[Dd];
  __shared__ __attribute__((aligned(16))) unsigned short sLbf[Dd];
  const int i = blockIdx.x;
  const int t = threadIdx.x;

  if (t < Dd) sx[t] = x[i * Dd + t];
  __syncthreads();

  if (t < Dd) {
    const float4* wrow = (const float4*)(Win + t * Dd);
    float a0 = 0.f, a1 = 0.f, a2 = 0.f, a3 = 0.f;
#pragma unroll
    for (int d4 = 0; d4 < Dd / 4; d4 += 4) {
      float4 w0 = wrow[d4+0], w1 = wrow[d4+1], w2 = wrow[d4+2], w3 = wrow[d4+3];
      a0 += sx[4*d4+ 0]*w0.x + sx[4*d4+ 1]*w0.y + sx[4*d4+ 2]*w0.z + sx[4*d4+ 3]*w0.w;
      a1 += sx[4*d4+ 4]*w1.x + sx[4*d4+ 5]*w1.y + sx[4*d4+ 6]*w1.z + sx[4*d4+ 7]*w1.w;
      a2 += sx[4*d4+ 8]*w2.x + sx[4*d4+ 9]*w2.y + sx[4*d4+10]*w2.z + sx[4*d4+11]*w2.w;
      a3 += sx[4*d4+12]*w3.x + sx[4*d4+13]*w3.y + sx[4*d4+14]*w3.z + sx[4*d4+15]*w3.w;
    }
    float l = ((a0 + a1) + (a2 + a3)) + bin[t];
    sLi[t]  = l;
    sLbf[t] = f2bf(l);
  }
  __syncthreads();

  // left_sw row i: 16 chunks of 16B, swizzled placement within the 256B row
  if (t < 16) {
    i32x4 v = *(const i32x4*)(sLbf + t * 8);
    const int sw = (i & 7) << 4;
    *(i32x4*)((char*)left_sw + (size_t)i * 256 + ((t * 16) ^ sw)) = v;
  }

  // B_i: thread handles row r = t>>1, 64 elems starting at c0
  {
    const int r  = t >> 1;
    const int c0 = (t & 1) * 64;
    const int sw = (r & 7) << 4;
    const float4* wp = (const float4*)(Wout + r * Dd + c0);
    char* grow = (char*)B_sw + (size_t)i * 32768 + r * 256;
#pragma unroll
    for (int q = 0; q < 8; ++q) {
      float4 w0 = wp[2*q], w1 = wp[2*q+1];
      const float* lp = sLi + c0 + q * 8;
      unsigned int p0 = (unsigned int)f2bf(w0.x * lp[0]) | ((unsigned int)f2bf(w0.y * lp[1]) << 16);
      unsigned int p1 = (unsigned int)f2bf(w0.z * lp[2]) | ((unsigned int)f2bf(w0.w * lp[3]) << 16);
      unsigned int p2 = (unsigned int)f2bf(w1.x * lp[4]) | ((unsigned int)f2bf(w1.y * lp[5]) << 16);
      unsigned int p3 = (unsigned int)f2bf(w1.z * lp[6]) | ((unsigned int)f2bf(w1.w * lp[7]) << 16);
      i32x4 vb; vb[0] = (int)p0; vb[1] = (int)p1; vb[2] = (int)p2; vb[3] = (int)p3;
      __builtin_nontemporal_store(vb, (i32x4*)(grow + ((c0 * 2 + q * 16) ^ sw)));
    }
  }
}

// k_outer_fast: one block per (i, j-tile). Pure-copy staging via
// global_load_lds (sources pre-swizzled), MFMA C[j][e], R1-proven epilogue.
// XCD-grouped mapping: bid&7 = xcd owns i in [xcd*96, xcd*96+96).
__global__ __launch_bounds__(256, 2)
void k_outer_fast(const unsigned short* __restrict__ left_sw,
                  const unsigned short* __restrict__ B_sw,
                  const float* __restrict__ bout, float* __restrict__ out) {
  __shared__ __attribute__((aligned(16))) unsigned short sA[128 * 128];
  __shared__ __attribute__((aligned(16))) unsigned short sB[128 * 128];

  const int bid = blockIdx.x;
  const int xcd = bid & 7;
  const int k6  = bid >> 3;            // 0..575
  const int i   = xcd * 96 + (k6 / 6);
  const int jt  = k6 % 6;

  const int t    = threadIdx.x;
  const int wid  = t >> 6;
  const int lane = t & 63;
  const int l15  = lane & 15;

  float bias[8];
#pragma unroll
  for (int n = 0; n < 8; ++n) bias[n] = bout[n * 16 + l15];

  const char* gA = (const char*)left_sw + (size_t)jt * 32768;
  const char* gB = (const char*)B_sw + (size_t)i * 32768;
#pragma unroll
  for (int it = 0; it < 8; ++it) {
    const int off = t * 16 + it * 4096;
    __builtin_amdgcn_global_load_lds(
        (const __attribute__((address_space(1))) void*)(gA + off),
        (__attribute__((address_space(3))) void*)((char*)sA + off), 16, 0, 0);
    __builtin_amdgcn_global_load_lds(
        (const __attribute__((address_space(1))) void*)(gB + off),
        (__attribute__((address_space(3))) void*)((char*)sB + off), 16, 0, 0);
  }
  __syncthreads();   // drains vmcnt (global_load_lds) + barrier

  const int sw  = (l15 & 7) << 4;
  const int kqb = (lane >> 4) * 16;
  const char* sAc = (const char*)sA;
  const char* sBc = (const char*)sB;

  f32x4 acc[2][8] = {};
#pragma unroll
  for (int kb = 0; kb < 4; ++kb) {
    const int cb = (kb * 64 + kqb) ^ sw;
    bf16x8 a0 = *(const bf16x8*)(sAc + (wid * 32 +      l15) * 256 + cb);
    bf16x8 a1 = *(const bf16x8*)(sAc + (wid * 32 + 16 + l15) * 256 + cb);
#pragma unroll
    for (int n = 0; n < 8; ++n) {
      bf16x8 b = *(const bf16x8*)(sBc + (n * 16 + l15) * 256 + cb);
      acc[0][n] = __builtin_amdgcn_mfma_f32_16x16x32_bf16(a0, b, acc[0][n], 0, 0, 0);
      acc[1][n] = __builtin_amdgcn_mfma_f32_16x16x32_bf16(a1, b, acc[1][n], 0, 0, 0);
    }
  }

  // R1-proven epilogue: row(j) = (lane>>4)*4 + r, col(e) = n*16 + l15
#pragma unroll
  for (int jb = 0; jb < 2; ++jb) {
#pragma unroll
    for (int r = 0; r < 4; ++r) {
      const int j = jt * 128 + wid * 32 + jb * 16 + (lane >> 4) * 4 + r;
      float* orow = out + ((size_t)i * Nn + j) * Dd;
#pragma unroll
      for (int n = 0; n < 8; ++n) {
        __builtin_nontemporal_store(acc[jb][n][r] + bias[n], orow + n * 16 + l15);
      }
    }
  }
}

// ======================= fallback path (R1, proven 70.5us) =======================
__global__ __launch_bounds__(128)
void k_left(const float* __restrict__ x, const float* __restrict__ Win,
            const float* __restrict__ bin, unsigned short* __restrict__ left) {
  __shared__ float sx[Dd];
  const int i = blockIdx.x;
  const int e = threadIdx.x;
  sx[e] = x[i * Dd + e];
  __syncthreads();
  const float4* wrow = (const float4*)(Win + e * Dd);
  float a0 = 0.f, a1 = 0.f, a2 = 0.f, a3 = 0.f;
#pragma unroll
  for (int d4 = 0; d4 < Dd / 4; d4 += 4) {
    float4 w0 = wrow[d4+0], w1 = wrow[d4+1], w2 = wrow[d4+2], w3 = wrow[d4+3];
    a0 += sx[4*d4+ 0]*w0.x + sx[4*d4+ 1]*w0.y + sx[4*d4+ 2]*w0.z + sx[4*d4+ 3]*w0.w;
    a1 += sx[4*d4+ 4]*w1.x + sx[4*d4+ 5]*w1.y + sx[4*d4+ 6]*w1.z + sx[4*d4+ 7]*w1.w;
    a2 += sx[4*d4+ 8]*w2.x + sx[4*d4+ 9]*w2.y + sx[4*d4+10]*w2.z + sx[4*d4+11]*w2.w;
    a3 += sx[4*d4+12]*w3.x + sx[4*d4+13]*w3.y + sx[4*d4+14]*w3.z + sx[4*d4+15]*w3.w;
  }
  left[i * Dd + e] = f2bf(((a0 + a1) + (a2 + a3)) + bin[e]);
}

__global__ __launch_bounds__(256, 2)
void k_outer_r1(const unsigned short* __restrict__ left, const float* __restrict__ Wout,
                const float* __restrict__ bout, float* __restrict__ out) {
  __shared__ __attribute__((aligned(16))) unsigned short sA[128 * LDP];
  __shared__ __attribute__((aligned(16))) unsigned short sB[128 * LDP];
  __shared__ float sLi[Dd];
  __shared__ float sBo[Dd];

  const int jt = blockIdx.x;
  const int i  = blockIdx.y;
  const int t  = threadIdx.x;

  if (t < Dd) { sLi[t] = bf2f(left[i * Dd + t]); sBo[t] = bout[t]; }
  __syncthreads();
  {
    const int row = t >> 4;
    const int c8  = (t & 15) * 8;
#pragma unroll
    for (int it = 0; it < 8; ++it) {
      const int r = row + it * 16;
      i32x4 va = *(const i32x4*)(left + (jt * 128 + r) * Dd + c8);
      *(i32x4*)(sA + r * LDP + c8) = va;
      const float4* wp = (const float4*)(Wout + r * Dd + c8);
      float4 w0 = wp[0], w1 = wp[1];
      unsigned int p0 = (unsigned int)f2bf(w0.x * sLi[c8+0]) | ((unsigned int)f2bf(w0.y * sLi[c8+1]) << 16);
      unsigned int p1 = (unsigned int)f2bf(w0.z * sLi[c8+2]) | ((unsigned int)f2bf(w0.w * sLi[c8+3]) << 16);
      unsigned int p2 = (unsigned int)f2bf(w1.x * sLi[c8+4]) | ((unsigned int)f2bf(w1.y * sLi[c8+5]) << 16);
      unsigned int p3 = (unsigned int)f2bf(w1.z * sLi[c8+6]) | ((unsigned int)f2bf(w1.w * sLi[c8+7]) << 16);
      i32x4 vb; vb[0] = (int)p0; vb[1] = (int)p1; vb[2] = (int)p2; vb[3] = (int)p3;
      *(i32x4*)(sB + r * LDP + c8) = vb;
    }
  }
  __syncthreads();

  const int wid  = t >> 6;
  const int lane = t & 63;
  const int l15  = lane & 15;
  const int kq   = (lane >> 4) * 8;

  f32x4 acc[2][8] = {};
#pragma unroll
  for (int kb = 0; kb < 4; ++kb) {
    const int k = kb * 32 + kq;
    bf16x8 a0 = *(const bf16x8*)(sA + (wid * 32 +      l15) * LDP + k);
    bf16x8 a1 = *(const bf16x8*)(sA + (wid * 32 + 16 + l15) * LDP + k);
#pragma unroll
    for (int n = 0; n < 8; ++n) {
      bf16x8 b = *(const bf16x8*)(sB + (n * 16 + l15) * LDP + k);
      acc[0][n] = __builtin_amdgcn_mfma_f32_16x16x32_bf16(a0, b, acc[0][n], 0, 0, 0);
      acc[1][n] = __builtin_amdgcn_mfma_f32_16x16x32_bf16(a1, b, acc[1][n], 0, 0, 0);
    }
  }
#pragma unroll
  for (int jb = 0; jb < 2; ++jb) {
#pragma unroll
    for (int r = 0; r < 4; ++r) {
      const int j = jt * 128 + wid * 32 + jb * 16 + (lane >> 4) * 4 + r;
      float* orow = out + ((size_t)i * Nn + j) * Dd;
#pragma unroll
      for (int n = 0; n < 8; ++n) {
        const int e = n * 16 + l15;
        orow[e] = acc[jb][n][r] + sBo[e];
      }
    }
  }
}

extern "C" void kernel_launch(void* const* d_in, const int* in_sizes, int n_in,
                              void* d_out, int out_size, void* d_ws, size_t ws_size,
                              hipStream_t stream) {
  const float* x    = (const float*)d_in[0];
  const float* Win  = (const float*)d_in[1];
  const float* bin  = (const float*)d_in[2];
  const float* Wout = (const float*)d_in[3];
  const float* bout = (const float*)d_in[4];
  float* out = (float*)d_out;

  const size_t NEED = 262144 + (size_t)Nn * 32768;   // left_sw + B_sw = 25.4 MB
  if (ws_size >= NEED) {
    unsigned short* left_sw = (unsigned short*)d_ws;
    unsigned short* B_sw    = (unsigned short*)((char*)d_ws + 262144);
    k_prep<<<Nn, 256, 0, stream>>>(x, Win, bin, Wout, left_sw, B_sw);
    k_outer_fast<<<Nn * 6, 256, 0, stream>>>(left_sw, B_sw, bout, out);
  } else {
    unsigned short* left = (unsigned short*)d_ws;    // 192 KiB
    k_left<<<Nn, Dd, 0, stream>>>(x, Win, bin, left);
    dim3 grid(Nn / 128, Nn);
    k_outer_r1<<<grid, 256, 0, stream>>>(left, Wout, bout, out);
  }
}

// Round 6
// 67.064 us; speedup vs baseline: 2.0517x; 2.0517x over previous
//
#include <hip/hip_runtime.h>

#define Nn 768
#define Dd 128
#define LDP 136   // padded bf16 row stride (272 B -> bank-conflict-free-ish)

typedef __attribute__((ext_vector_type(8))) short bf16x8;
typedef __attribute__((ext_vector_type(4))) float f32x4;
typedef __attribute__((ext_vector_type(4))) int   i32x4;

static __device__ __forceinline__ unsigned short f2bf(float f) {
  unsigned int u = __builtin_bit_cast(unsigned int, f);
  u += 0x7fffu + ((u >> 16) & 1u);   // RNE
  return (unsigned short)(u >> 16);
}
static __device__ __forceinline__ float bf2f(unsigned short h) {
  unsigned int u = ((unsigned int)h) << 16;
  return __builtin_bit_cast(float, u);
}
// packed f32 pair -> [bf16(hi):bf16(lo)] in one VALU op (RNE)
static __device__ __forceinline__ unsigned int cvtpk(float lo, float hi) {
  unsigned int r;
  asm("v_cvt_pk_bf16_f32 %0, %1, %2" : "=v"(r) : "v"(lo), "v"(hi));
  return r;
}

// left[i][e] = sum_d x[i][d] * W_in[e][d] + b_in[e], stored bf16
__global__ __launch_bounds__(128)
void k_left(const float* __restrict__ x, const float* __restrict__ Win,
            const float* __restrict__ bin, unsigned short* __restrict__ left) {
  __shared__ float sx[Dd];
  const int i = blockIdx.x;
  const int e = threadIdx.x;
  sx[e] = x[i * Dd + e];
  __syncthreads();
  const float4* wrow = (const float4*)(Win + e * Dd);
  float a0 = 0.f, a1 = 0.f, a2 = 0.f, a3 = 0.f;
#pragma unroll
  for (int d4 = 0; d4 < Dd / 4; d4 += 4) {
    float4 w0 = wrow[d4+0], w1 = wrow[d4+1], w2 = wrow[d4+2], w3 = wrow[d4+3];
    a0 += sx[4*d4+ 0]*w0.x + sx[4*d4+ 1]*w0.y + sx[4*d4+ 2]*w0.z + sx[4*d4+ 3]*w0.w;
    a1 += sx[4*d4+ 4]*w1.x + sx[4*d4+ 5]*w1.y + sx[4*d4+ 6]*w1.z + sx[4*d4+ 7]*w1.w;
    a2 += sx[4*d4+ 8]*w2.x + sx[4*d4+ 9]*w2.y + sx[4*d4+10]*w2.z + sx[4*d4+11]*w2.w;
    a3 += sx[4*d4+12]*w3.x + sx[4*d4+13]*w3.y + sx[4*d4+14]*w3.z + sx[4*d4+15]*w3.w;
  }
  left[i * Dd + e] = f2bf(((a0 + a1) + (a2 + a3)) + bin[e]);
}

// out[i, j, e] = sum_d left[j][d] * (W_out[e][d]*left[i][d]) + b_out[e]
// R1 skeleton, three deltas: (1) cvt_pk staging, (2) A-fragments straight
// from global left (no sA -> LDS 35.8 KB), (3) 3 blocks/CU.
__global__ __launch_bounds__(256, 3)
void k_outer(const unsigned short* __restrict__ left, const float* __restrict__ Wout,
             const float* __restrict__ bout, float* __restrict__ out) {
  __shared__ __attribute__((aligned(16))) unsigned short sB[128 * LDP]; // Wout[e][d]*l_i[d]
  __shared__ float sLi[Dd];
  __shared__ float sBo[Dd];

  const int jt = blockIdx.x;   // 0..5
  const int i  = blockIdx.y;   // 0..767
  const int t  = threadIdx.x;  // 0..255

  if (t < Dd) {
    sLi[t] = bf2f(left[i * Dd + t]);
    sBo[t] = bout[t];
  }
  __syncthreads();

  // Stage sB: thread covers col-chunk c8 (fixed) x 8 rows; sLi hoisted to regs.
  {
    const int row = t >> 4;          // 0..15
    const int c8  = (t & 15) * 8;
    float l[8];
#pragma unroll
    for (int q = 0; q < 8; ++q) l[q] = sLi[c8 + q];   // 2x ds_read_b128
#pragma unroll
    for (int it = 0; it < 8; ++it) {
      const int r = row + it * 16;   // 0..127
      const float4* wp = (const float4*)(Wout + r * Dd + c8);
      float4 w0 = wp[0], w1 = wp[1];
      i32x4 vb;
      vb[0] = (int)cvtpk(w0.x * l[0], w0.y * l[1]);
      vb[1] = (int)cvtpk(w0.z * l[2], w0.w * l[3]);
      vb[2] = (int)cvtpk(w1.x * l[4], w1.y * l[5]);
      vb[3] = (int)cvtpk(w1.z * l[6], w1.w * l[7]);
      *(i32x4*)(sB + r * LDP + c8) = vb;
    }
  }
  __syncthreads();

  const int wid  = t >> 6;        // wave 0..3 -> j rows [wid*32, wid*32+32)
  const int lane = t & 63;
  const int l15  = lane & 15;
  const int kq   = (lane >> 4) * 8;

  // A-fragments directly from global left (L2/L3-resident, 192 KB total)
  const unsigned short* gA = left + (size_t)(jt * 128 + wid * 32 + l15) * Dd;

  f32x4 acc[2][8] = {};   // [j-frag][e-chunk]
#pragma unroll
  for (int kb = 0; kb < 4; ++kb) {
    const int k = kb * 32 + kq;
    bf16x8 a0 = *(const bf16x8*)(gA + k);
    bf16x8 a1 = *(const bf16x8*)(gA + 16 * Dd + k);
#pragma unroll
    for (int n = 0; n < 8; ++n) {
      bf16x8 b = *(const bf16x8*)(sB + (n * 16 + l15) * LDP + k);
      acc[0][n] = __builtin_amdgcn_mfma_f32_16x16x32_bf16(a0, b, acc[0][n], 0, 0, 0);
      acc[1][n] = __builtin_amdgcn_mfma_f32_16x16x32_bf16(a1, b, acc[1][n], 0, 0, 0);
    }
  }

  // R1-proven epilogue: row(j) = (lane>>4)*4 + r, col(e) = n*16 + l15. Plain stores.
#pragma unroll
  for (int jb = 0; jb < 2; ++jb) {
#pragma unroll
    for (int r = 0; r < 4; ++r) {
      const int j = jt * 128 + wid * 32 + jb * 16 + (lane >> 4) * 4 + r;
      float* orow = out + ((size_t)i * Nn + j) * Dd;
#pragma unroll
      for (int n = 0; n < 8; ++n) {
        const int e = n * 16 + l15;
        orow[e] = acc[jb][n][r] + sBo[e];
      }
    }
  }
}

extern "C" void kernel_launch(void* const* d_in, const int* in_sizes, int n_in,
                              void* d_out, int out_size, void* d_ws, size_t ws_size,
                              hipStream_t stream) {
  const float* x    = (const float*)d_in[0];
  const float* Win  = (const float*)d_in[1];
  const float* bin  = (const float*)d_in[2];
  const float* Wout = (const float*)d_in[3];
  const float* bout = (const float*)d_in[4];
  float* out = (float*)d_out;
  unsigned short* left = (unsigned short*)d_ws;  // 768*128 bf16 = 192 KiB

  k_left<<<Nn, Dd, 0, stream>>>(x, Win, bin, left);
  dim3 grid(Nn / 128, Nn);
  k_outer<<<grid, 256, 0, stream>>>(left, Wout, bout, out);
}